// Round 15
// baseline (122.787 us; speedup 1.0000x reference)
//
#include <hip/hip_runtime.h>
#include <hip/hip_fp16.h>
#include <math.h>

#define PI_D 3.141592653589793

typedef _Float16 h2 __attribute__((ext_vector_type(2)));
typedef _Float16 h4 __attribute__((ext_vector_type(4)));
typedef _Float16 h8 __attribute__((ext_vector_type(8)));
typedef unsigned short us8 __attribute__((ext_vector_type(8)));
typedef __fp16 f16v2 __attribute__((ext_vector_type(2)));
typedef __fp16 f16v8 __attribute__((ext_vector_type(8)));
typedef float f32x4 __attribute__((ext_vector_type(4)));

#define STR1 264     // gl1h/gr1h row stride in halves (528 B; 33 h8)
#define STR2H 72     // gl2h/gr2h fp16 row stride in halves (144 B)
#define NS 4         // samples per block

#define SV(v, a, b) __builtin_shufflevector(v, v, a, b)

static __device__ __forceinline__ h2 pack_h2(float a, float b) {
    return __builtin_bit_cast(h2, __builtin_amdgcn_cvt_pkrtz(a, b));
}

static __device__ __forceinline__ float fdot2(h2 a, h2 b, float c) {
    return __builtin_amdgcn_fdot2(__builtin_bit_cast(f16v2, a),
                                  __builtin_bit_cast(f16v2, b), c, false);
}

static __device__ __forceinline__ h8 habs8(h8 x) {
    us8 u = __builtin_bit_cast(us8, x);
    us8 m = {0x7fff, 0x7fff, 0x7fff, 0x7fff, 0x7fff, 0x7fff, 0x7fff, 0x7fff};
    return __builtin_bit_cast(h8, (us8)(u & m));
}

static __device__ __forceinline__ f32x4 mfma16(h8 a, h8 b, f32x4 c) {
    return __builtin_amdgcn_mfma_f32_16x16x32_f16(
        __builtin_bit_cast(f16v8, a), __builtin_bit_cast(f16v8, b), c, 0, 0, 0);
}

static __device__ __forceinline__ void wave_fence() {
    asm volatile("" ::: "memory");
#if __has_builtin(__builtin_amdgcn_wave_barrier)
    __builtin_amdgcn_wave_barrier();
#endif
    asm volatile("" ::: "memory");
}

// ---- pre-pass: pack weights to fp16 (round-10 layouts) ----
__global__ __launch_bounds__(256) void pack_weights_kernel(
    const float* __restrict__ Wl2, const float* __restrict__ Wr2,
    const float* __restrict__ fc1_w, const float* __restrict__ fc2_w,
    h8* __restrict__ ws)
{
    int idx = blockIdx.x * 256 + threadIdx.x;
    if (idx < 4096) {
        const float* W = idx < 2048 ? Wl2 : Wr2;
        int t = idx & 2047;
        int ntile = t >> 9, rem = t & 511;
        int kchunk = rem >> 6, lane = rem & 63;
        int n = ntile * 16 + (lane & 15);
        int k0 = kchunk * 32 + (lane >> 4) * 8;
        h8 o;
        #pragma unroll
        for (int j = 0; j < 8; ++j) o[j] = (_Float16)W[(k0 + j) * 64 + n];
        ws[idx] = o;
    } else if (idx < 6144) {
        int t = idx - 4096;
        int k2 = t >> 6, c = t & 63;
        h8 o;
        #pragma unroll
        for (int q = 0; q < 4; ++q) {
            o[2 * q]     = (_Float16)fc1_w[(2 * k2) * 256 + 4 * c + q];
            o[2 * q + 1] = (_Float16)fc1_w[(2 * k2 + 1) * 256 + 4 * c + q];
        }
        ws[idx] = o;
    } else {
        int t = idx - 6144;
        int k2 = t >> 6, c = t & 63;
        h8 o;
        #pragma unroll
        for (int q = 0; q < 4; ++q) {
            o[2 * q]     = (_Float16)fc2_w[(2 * k2) * 256 + 4 * c + q];
            o[2 * q + 1] = (_Float16)fc2_w[(2 * k2 + 1) * 256 + 4 * c + q];
        }
        ws[idx] = o;
    }
}

__global__ __launch_bounds__(256, 1) void actor_fused_kernel(
    const float* __restrict__ state24,
    const float* __restrict__ Wl1, const float* __restrict__ Wr1,
    const float* __restrict__ att1, const float* __restrict__ b1,
    const float* __restrict__ att2, const float* __restrict__ b2,
    const float* __restrict__ fc1_b, const float* __restrict__ fc2_b,
    const float* __restrict__ fc3_w, const float* __restrict__ fc3_b,
    const h8* __restrict__ wsL, const h8* __restrict__ wsR,
    const h8* __restrict__ wsF1, const h8* __restrict__ wsF2,
    float* __restrict__ out, int B)
{
    const int bix = blockIdx.x;
    const int tid = threadIdx.x;
    const int smpb = NS * bix;
    if (smpb >= B) return;

    __shared__ float sinL[20], cosL[20], laserL[NS][20], robotL[NS][4];
    __shared__ __align__(16) h2 attLh[128];
    __shared__ __align__(16) h2 att2Lh[32];
    __shared__ __align__(16) _Float16 gr1h[NS][22 * STR1];
    __shared__ __align__(16) union {
        struct { _Float16 gl1h[NS][22 * STR1];
                 float ePf[NS][128 * 24];
                 float uv[NS][168]; } p1;
        struct { _Float16 gl2h[NS][21 * STR2H];
                 _Float16 gr2h[NS][21 * STR2H];
                 _Float16 gl2hT[NS][64 * 32];
                 float e2[NS][32 * 24];
                 float u2v2[NS][42];
                 float red[NS][4][256];
                 _Float16 nfvh[NS][64]; _Float16 hah[NS][256]; _Float16 hbh[NS][256]; } p2;
    } U;

    // ---- setup ----
    if (tid < 20) {
        double step = (PI_D + 0.03) / 20.0;
        float bound = (float)(-PI_D / 2.0 - 0.03 + (double)tid * step);
        float ang = bound + (float)(PI_D / 20.0);
        sinL[tid] = sinf(ang);
        cosL[tid] = cosf(ang);
        #pragma unroll
        for (int s = 0; s < NS; ++s) {
            int sm = smpb + s; if (sm >= B) sm = B - 1;
            laserL[s][tid] = state24[sm * 24 + tid] * 0.1f;
        }
    }
    if (tid >= 32 && tid < 32 + 4 * NS) {
        int s = (tid - 32) >> 2, q = (tid - 32) & 3;
        int sm = smpb + s; if (sm >= B) sm = B - 1;
        robotL[s][q] = state24[sm * 24 + 20 + q];
    }
    if (tid < 128) {
        float2 ap = ((const float2*)att1)[tid];
        attLh[tid] = pack_h2(0.4f * ap.x, 0.4f * ap.y);
    }
    if (tid >= 128 && tid < 160) {
        float2 ap = ((const float2*)att2)[tid - 128];
        att2Lh[tid - 128] = pack_h2(0.4f * ap.x, 0.4f * ap.y);
    }
    __syncthreads();

    // ================= L1 block: wave h owns head h, all NS samples =================
    {
        const int h = tid >> 6;
        const int lane = tid & 63;

        // ---- transform1: weights loaded once, used for all samples ----
        {
            const int cp = lane & 31;
            const int half = lane >> 5;
            const int d2 = h * 32 + cp;
            float2 wl[7], wr[7];
            #pragma unroll
            for (int k = 0; k < 7; k++) {
                wl[k] = ((const float2*)Wl1)[k * 128 + d2];
                wr[k] = ((const float2*)Wr1)[k * 128 + d2];
            }
            if (half == 0) {
                h2 zz2 = {};
                #pragma unroll
                for (int s = 0; s < NS; ++s) {
                    ((h2*)(U.p1.gl1h[s] + 21 * STR1))[d2] = zz2;
                    ((h2*)(gr1h[s] + 21 * STR1))[d2] = zz2;
                }
            }
            const int base = half * 11;
            #pragma unroll
            for (int nn = 0; nn < 11; ++nn) {
                int node = base + nn;
                if (node < 21) {
                    #pragma unroll
                    for (int s = 0; s < NS; ++s) {
                        float a0, a1, b0, b1v;
                        if (node < 20) {
                            float l = laserL[s][node], sv = sinL[node], c = cosL[node];
                            a0 = l * wl[0].x + sv * wl[1].x + c * wl[2].x;
                            a1 = l * wl[0].y + sv * wl[1].y + c * wl[2].y;
                            b0 = l * wr[0].x + sv * wr[1].x + c * wr[2].x;
                            b1v = l * wr[0].y + sv * wr[1].y + c * wr[2].y;
                        } else {
                            float r0 = robotL[s][0], r1 = robotL[s][1], r2 = robotL[s][2], r3 = robotL[s][3];
                            a0 = r0 * wl[3].x + r1 * wl[4].x + r2 * wl[5].x + r3 * wl[6].x;
                            a1 = r0 * wl[3].y + r1 * wl[4].y + r2 * wl[5].y + r3 * wl[6].y;
                            b0 = r0 * wr[3].x + r1 * wr[4].x + r2 * wr[5].x + r3 * wr[6].x;
                            b1v = r0 * wr[3].y + r1 * wr[4].y + r2 * wr[5].y + r3 * wr[6].y;
                        }
                        ((h2*)(U.p1.gl1h[s] + node * STR1))[d2] = pack_h2(a0, a1);
                        ((h2*)(gr1h[s] + node * STR1))[d2] = pack_h2(b0, b1v);
                    }
                }
            }
        }
        wave_fence();

        // ---- logits1 (abs part) + u/v, all samples ----
        {
            h2 ar[32];
            #pragma unroll
            for (int q = 0; q < 32; ++q) ar[q] = attLh[h * 32 + q];

            #pragma unroll
            for (int s = 0; s < NS; ++s) {
                for (int it = 0; it < 7; ++it) {
                    int q = it * 64 + lane;
                    if (q < 441) {
                        int i = q / 21;
                        int j = q - i * 21;
                        const h8* gA8 = (const h8*)(U.p1.gl1h[s] + j * STR1 + h * 64);
                        const h8* gB8 = (const h8*)(gr1h[s] + i * STR1 + h * 64);
                        float m0 = 0.f, m1 = 0.f;
                        #pragma unroll
                        for (int ch = 0; ch < 8; ++ch) {
                            h8 x = gA8[ch] + gB8[ch];
                            h8 ax = habs8(x);
                            m0 = fdot2(SV(ax, 0, 1), ar[ch * 4 + 0], m0);
                            m1 = fdot2(SV(ax, 2, 3), ar[ch * 4 + 1], m1);
                            m0 = fdot2(SV(ax, 4, 5), ar[ch * 4 + 2], m0);
                            m1 = fdot2(SV(ax, 6, 7), ar[ch * 4 + 3], m1);
                        }
                        U.p1.ePf[s][(h * 32 + i) * 24 + j] = m0 + m1;
                    }
                }
            }
            if (lane < 42) {
                int isV = lane >= 21;
                int idx = isV ? lane - 21 : lane;
                #pragma unroll
                for (int s = 0; s < NS; ++s) {
                    const _Float16* rowp = (isV ? (const _Float16*)gr1h[s]
                                                : (const _Float16*)U.p1.gl1h[s]) + idx * STR1 + h * 64;
                    const h8* row8 = (const h8*)rowp;
                    float l0 = 0.f, l1 = 0.f;
                    #pragma unroll
                    for (int ch = 0; ch < 8; ++ch) {
                        h8 g = row8[ch];
                        l0 = fdot2(SV(g, 0, 1), ar[ch * 4 + 0], l0);
                        l1 = fdot2(SV(g, 2, 3), ar[ch * 4 + 1], l1);
                        l0 = fdot2(SV(g, 4, 5), ar[ch * 4 + 2], l0);
                        l1 = fdot2(SV(g, 6, 7), ar[ch * 4 + 3], l1);
                    }
                    U.p1.uv[s][(isV ? 84 : 0) + h * 21 + idx] = l0 + l1;
                }
            }
        }
        wave_fence();

        // ---- softmax1: 84 rows (s,i) per head, lanes loop; zero rows 21..31 all samples ----
        for (int z = lane; z < 84; z += 64) {
            int s = z / 21;
            int i = z - s * 21;
            int r = h * 32 + i;
            float* row = U.p1.ePf[s] + r * 24;
            const float* uu = U.p1.uv[s] + h * 21;
            float vi = 1.5f * U.p1.uv[s][84 + h * 21 + i];
            float ebuf[21];
            float m = -1e30f;
            #pragma unroll
            for (int j = 0; j < 21; j++) {
                float e = row[j] + 1.5f * uu[j] + vi;
                ebuf[j] = e;
                m = fmaxf(m, e);
            }
            float sum = 0.f;
            #pragma unroll
            for (int j = 0; j < 21; j++) { float v = __expf(ebuf[j] - m); ebuf[j] = v; sum += v; }
            float rinv = 1.f / sum;
            h8* hp8 = (h8*)(U.p1.ePf[s]) + r * 6;
            h8 o0, o1, o2;
            #pragma unroll
            for (int q = 0; q < 8; ++q) o0[q] = (_Float16)(ebuf[q] * rinv);
            #pragma unroll
            for (int q = 0; q < 8; ++q) o1[q] = (_Float16)(ebuf[8 + q] * rinv);
            #pragma unroll
            for (int q = 0; q < 5; ++q) o2[q] = (_Float16)(ebuf[16 + q] * rinv);
            o2[5] = (_Float16)0.f; o2[6] = (_Float16)0.f; o2[7] = (_Float16)0.f;
            h8 zz = {};
            hp8[0] = o0; hp8[1] = o1; hp8[2] = o2;
            hp8[3] = zz; hp8[4] = zz; hp8[5] = zz;
        }
        {   // zero fp16 A-frag rows (h, 21..31) x NS samples: 66 h8 per sample
            h8 zz = {};
            for (int z = lane; z < 66 * NS; z += 64) {
                int s = z / 66;
                int zz2 = z - s * 66;
                int rr = zz2 / 6, slot = zz2 - rr * 6;
                ((h8*)U.p1.ePf[s])[(h * 32 + 21 + rr) * 6 + slot] = zz;
            }
        }
        wave_fence();

        // ---- agg1 via MFMA, all samples; bias loaded once per col ----
        {
            const int mcol = lane & 15;
            const int quad = lane >> 4;
            h8 A0s[NS], A1s[NS];
            #pragma unroll
            for (int s = 0; s < NS; ++s) {
                const h8* Af = (const h8*)U.p1.ePf[s];
                A0s[s] = Af[(h * 32 + mcol) * 6 + quad];
                A1s[s] = Af[(h * 32 + 16 + mcol) * 6 + quad];
            }
            int rowoff[8];
            #pragma unroll
            for (int jj = 0; jj < 8; ++jj) {
                int rr = quad * 8 + jj;
                rowoff[jj] = (rr > 21 ? 21 : rr) * STR1;
            }
            const int colbase = h * 64 + mcol;
            f32x4 z4 = {0.f, 0.f, 0.f, 0.f};
            #pragma unroll
            for (int t = 0; t < 4; ++t) {
                int col = colbase + t * 16;
                float bb = b1[col];
                #pragma unroll
                for (int s = 0; s < NS; ++s) {
                    h8 bv;
                    #pragma unroll
                    for (int jj = 0; jj < 8; ++jj) bv[jj] = U.p1.gl1h[s][rowoff[jj] + col];
                    f32x4 d0 = mfma16(A0s[s], bv, z4);
                    f32x4 d1 = mfma16(A1s[s], bv, z4);
                    #pragma unroll
                    for (int r = 0; r < 4; ++r) {
                        int n0 = quad * 4 + r;
                        float v = d0[r] + bb;
                        v = v > 0.f ? v : __expf(v) - 1.f;
                        gr1h[s][n0 * STR1 + col] = (_Float16)v;
                        int n1 = 16 + quad * 4 + r;
                        if (n1 < 21) {
                            float w2 = d1[r] + bb;
                            w2 = w2 > 0.f ? w2 : __expf(w2) - 1.f;
                            gr1h[s][n1 * STR1 + col] = (_Float16)w2;
                        }
                    }
                }
            }
        }
    }
    __syncthreads();
    // ================= end L1 block =================

    // ---- layer-2 transforms via MFMA; B-frags loaded once per kc, all samples ----
    {
        const int lane = tid & 63;
        const int w = tid >> 6;
        const int mrow = lane & 15;
        const int quad = lane >> 4;
        int rowA1 = 16 + mrow; if (rowA1 > 21) rowA1 = 21;
        const h8* bL = wsL + w * 512 + lane;
        const h8* bR = wsR + w * 512 + lane;
        f32x4 aL0[NS], aL1[NS], aR0[NS], aR1[NS];
        #pragma unroll
        for (int s = 0; s < NS; ++s) {
            aL0[s] = (f32x4){0.f, 0.f, 0.f, 0.f}; aL1[s] = (f32x4){0.f, 0.f, 0.f, 0.f};
            aR0[s] = (f32x4){0.f, 0.f, 0.f, 0.f}; aR1[s] = (f32x4){0.f, 0.f, 0.f, 0.f};
        }
        #pragma unroll
        for (int kc = 0; kc < 8; ++kc) {
            h8 BL = bL[kc * 64];
            h8 BR = bR[kc * 64];
            #pragma unroll
            for (int s = 0; s < NS; ++s) {
                h8 A0 = *(const h8*)(gr1h[s] + mrow * STR1 + quad * 8 + kc * 32);
                h8 A1 = *(const h8*)(gr1h[s] + rowA1 * STR1 + quad * 8 + kc * 32);
                aL0[s] = mfma16(A0, BL, aL0[s]);
                aL1[s] = mfma16(A1, BL, aL1[s]);
                aR0[s] = mfma16(A0, BR, aR0[s]);
                aR1[s] = mfma16(A1, BR, aR1[s]);
            }
        }
        const int col = w * 16 + mrow;
        #pragma unroll
        for (int s = 0; s < NS; ++s) {
            #pragma unroll
            for (int r = 0; r < 4; ++r) {
                int row0 = quad * 4 + r;
                U.p2.gl2h[s][row0 * STR2H + col] = (_Float16)aL0[s][r];
                U.p2.gr2h[s][row0 * STR2H + col] = (_Float16)aR0[s][r];
                int row1 = 16 + row0;
                if (row1 < 21) {
                    U.p2.gl2h[s][row1 * STR2H + col] = (_Float16)aL1[s][r];
                    U.p2.gr2h[s][row1 * STR2H + col] = (_Float16)aR1[s][r];
                }
            }
            h2 lo0 = pack_h2(aL0[s][0], aL0[s][1]);
            h2 hi0 = pack_h2(aL0[s][2], aL0[s][3]);
            h4 p0 = __builtin_shufflevector(lo0, hi0, 0, 1, 2, 3);
            *(h4*)(U.p2.gl2hT[s] + col * 32 + quad * 4) = p0;
            h2 lo1 = pack_h2(aL1[s][0], aL1[s][1]);
            h2 hi1 = pack_h2(aL1[s][2], aL1[s][3]);
            h4 p1 = __builtin_shufflevector(lo1, hi1, 0, 1, 2, 3);
            *(h4*)(U.p2.gl2hT[s] + col * 32 + 16 + quad * 4) = p1;
        }
    }
    __syncthreads();

    // ---- layer-2 logits (abs part) all samples + u2/v2 in spare slots ----
    {
        h2 ar2[32];
        #pragma unroll
        for (int q = 0; q < 32; ++q) ar2[q] = att2Lh[q];

        #pragma unroll
        for (int it = 0; it < 8; ++it) {
            int t = it * 256 + tid;
            if (t < 441 * NS) {
                int s = t / 441;
                int p = t - s * 441;
                int i = p / 21;
                int j = p - i * 21;
                const h8* gA8 = (const h8*)(U.p2.gl2h[s] + j * STR2H);
                const h8* gB8 = (const h8*)(U.p2.gr2h[s] + i * STR2H);
                float m0 = 0.f, m1 = 0.f;
                #pragma unroll
                for (int ch = 0; ch < 8; ++ch) {
                    h8 x = gA8[ch] + gB8[ch];
                    h8 ax = habs8(x);
                    m0 = fdot2(SV(ax, 0, 1), ar2[ch * 4 + 0], m0);
                    m1 = fdot2(SV(ax, 2, 3), ar2[ch * 4 + 1], m1);
                    m0 = fdot2(SV(ax, 4, 5), ar2[ch * 4 + 2], m0);
                    m1 = fdot2(SV(ax, 6, 7), ar2[ch * 4 + 3], m1);
                }
                U.p2.e2[s][i * 24 + j] = m0 + m1;
            } else if (t < 441 * NS + 42 * NS) {
                int u = t - 441 * NS;
                int s = u / 42;
                int r = u - s * 42;
                int isV = r >= 21;
                int idx = r - isV * 21;
                const _Float16* rowp = (isV ? U.p2.gr2h[s] : U.p2.gl2h[s]) + idx * STR2H;
                const h8* row8 = (const h8*)rowp;
                float l0 = 0.f, l1 = 0.f;
                #pragma unroll
                for (int ch = 0; ch < 8; ++ch) {
                    h8 g = row8[ch];
                    l0 = fdot2(SV(g, 0, 1), ar2[ch * 4 + 0], l0);
                    l1 = fdot2(SV(g, 2, 3), ar2[ch * 4 + 1], l1);
                    l0 = fdot2(SV(g, 4, 5), ar2[ch * 4 + 2], l0);
                    l1 = fdot2(SV(g, 6, 7), ar2[ch * 4 + 3], l1);
                }
                U.p2.u2v2[s][isV * 21 + idx] = l0 + l1;
            }
        }
    }
    __syncthreads();

    // ---- softmax-2 all samples -> fp16 A-frag; zero rows 21..31 all ----
    if (tid < 21 * NS) {
        int s = tid / 21;
        int i = tid - s * 21;
        float* row = U.p2.e2[s] + i * 24;
        const float* uu = U.p2.u2v2[s];
        float vi = 1.5f * U.p2.u2v2[s][21 + i];
        float ebuf[21];
        float m = -1e30f;
        #pragma unroll
        for (int j = 0; j < 21; j++) {
            float e = row[j] + 1.5f * uu[j] + vi;
            ebuf[j] = e;
            m = fmaxf(m, e);
        }
        float sum = 0.f;
        #pragma unroll
        for (int j = 0; j < 21; j++) { float v = __expf(ebuf[j] - m); ebuf[j] = v; sum += v; }
        float rinv = 1.f / sum;
        h8* hp8 = (h8*)(U.p2.e2[s]) + i * 6;
        h8 o0, o1, o2;
        #pragma unroll
        for (int q = 0; q < 8; ++q) o0[q] = (_Float16)(ebuf[q] * rinv);
        #pragma unroll
        for (int q = 0; q < 8; ++q) o1[q] = (_Float16)(ebuf[8 + q] * rinv);
        #pragma unroll
        for (int q = 0; q < 5; ++q) o2[q] = (_Float16)(ebuf[16 + q] * rinv);
        o2[5] = (_Float16)0.f; o2[6] = (_Float16)0.f; o2[7] = (_Float16)0.f;
        h8 zz = {};
        hp8[0] = o0; hp8[1] = o1; hp8[2] = o2;
        hp8[3] = zz; hp8[4] = zz; hp8[5] = zz;
    } else {
        h8 zz = {};
        for (int z = tid - 21 * NS; z < 66 * NS; z += 256 - 21 * NS) {
            int s = z / 66;
            int zz2 = z - s * 66;
            int rr = zz2 / 6, slot = zz2 - rr * 6;
            ((h8*)U.p2.e2[s])[(21 + rr) * 6 + slot] = zz;
        }
    }
    __syncthreads();

    // ---- agg2 + mean-pool via MFMA -> nfvh, all samples ----
    {
        const int lane = tid & 63;
        const int w = tid >> 6;
        const int mcol = lane & 15;
        const int quad = lane >> 4;
        const int col = w * 16 + mcol;
        float bb = b2[col];
        f32x4 z4 = {0.f, 0.f, 0.f, 0.f};
        #pragma unroll
        for (int s = 0; s < NS; ++s) {
            const h8* Af2 = (const h8*)U.p2.e2[s];
            h8 A0 = Af2[mcol * 6 + quad];
            h8 A1 = Af2[(16 + mcol) * 6 + quad];
            h8 bv = *(const h8*)(U.p2.gl2hT[s] + col * 32 + quad * 8);
            f32x4 d0 = mfma16(A0, bv, z4);
            f32x4 d1 = mfma16(A1, bv, z4);
            float sum = (d0[0] + d0[1]) + (d0[2] + d0[3])
                      + (d1[0] + d1[1]) + (d1[2] + d1[3]);
            sum += __shfl_xor(sum, 16, 64);
            sum += __shfl_xor(sum, 32, 64);
            if (quad == 0) U.p2.nfvh[s][col] = (_Float16)(sum * (1.f / 21.f) + bb);
        }
    }
    __syncthreads();

    // ---- FC1 (64 -> 256): weights loaded once, all samples ----
    {
        int c = tid & 63, g = tid >> 6;
        float4 acc[NS];
        #pragma unroll
        for (int s = 0; s < NS; ++s) acc[s] = (float4){0.f, 0.f, 0.f, 0.f};
        #pragma unroll
        for (int kk = 0; kk < 8; ++kk) {
            int k2 = g * 8 + kk;
            h8 w = wsF1[k2 * 64 + c];
            #pragma unroll
            for (int s = 0; s < NS; ++s) {
                h2 x = ((const h2*)U.p2.nfvh[s])[k2];
                acc[s].x = fdot2(SV(w, 0, 1), x, acc[s].x);
                acc[s].y = fdot2(SV(w, 2, 3), x, acc[s].y);
                acc[s].z = fdot2(SV(w, 4, 5), x, acc[s].z);
                acc[s].w = fdot2(SV(w, 6, 7), x, acc[s].w);
            }
        }
        #pragma unroll
        for (int s = 0; s < NS; ++s) ((float4*)U.p2.red[s][g])[c] = acc[s];
    }
    __syncthreads();
    {
        float bb = fc1_b[tid];
        #pragma unroll
        for (int s = 0; s < NS; ++s) {
            float v = U.p2.red[s][0][tid] + U.p2.red[s][1][tid]
                    + U.p2.red[s][2][tid] + U.p2.red[s][3][tid] + bb;
            U.p2.hah[s][tid] = (_Float16)fmaxf(v, 0.f);
        }
    }
    __syncthreads();

    // ---- FC2 (256 -> 256): weights loaded once, all samples ----
    {
        int c = tid & 63, g = tid >> 6;
        float4 acc[NS];
        #pragma unroll
        for (int s = 0; s < NS; ++s) acc[s] = (float4){0.f, 0.f, 0.f, 0.f};
#define FC2_STEP(q, p)                                                          \
        {                                                                       \
            int k2 = g * 32 + (q) * 4 + (p);                                    \
            h8 w = wsF2[k2 * 64 + c];                                           \
            _Pragma("unroll")                                                   \
            for (int s = 0; s < NS; ++s) {                                      \
                h2 x = __builtin_shufflevector(xa[s], xa[s], 2 * (p), 2 * (p) + 1); \
                acc[s].x = fdot2(SV(w, 0, 1), x, acc[s].x);                     \
                acc[s].y = fdot2(SV(w, 2, 3), x, acc[s].y);                     \
                acc[s].z = fdot2(SV(w, 4, 5), x, acc[s].z);                     \
                acc[s].w = fdot2(SV(w, 6, 7), x, acc[s].w);                     \
            }                                                                   \
        }
        #pragma unroll
        for (int q = 0; q < 8; ++q) {
            h8 xa[NS];
            #pragma unroll
            for (int s = 0; s < NS; ++s) xa[s] = ((const h8*)U.p2.hah[s])[g * 8 + q];
            FC2_STEP(q, 0)
            FC2_STEP(q, 1)
            FC2_STEP(q, 2)
            FC2_STEP(q, 3)
        }
#undef FC2_STEP
        #pragma unroll
        for (int s = 0; s < NS; ++s) ((float4*)U.p2.red[s][g])[c] = acc[s];
    }
    __syncthreads();
    {
        float bb = fc2_b[tid];
        #pragma unroll
        for (int s = 0; s < NS; ++s) {
            float v = U.p2.red[s][0][tid] + U.p2.red[s][1][tid]
                    + U.p2.red[s][2][tid] + U.p2.red[s][3][tid] + bb;
            U.p2.hbh[s][tid] = (_Float16)fmaxf(v, 0.f);
        }
    }
    __syncthreads();

    // ---- FC3 (256 -> 2) + tanh: wave g handles sample g, both outputs ----
    {
        int s = tid >> 6;
        int l = tid & 63;
        float w0 = fc3_w[l * 2 + 0],       w1 = fc3_w[l * 2 + 1];
        float w2 = fc3_w[(l + 64) * 2],    w3 = fc3_w[(l + 64) * 2 + 1];
        float w4 = fc3_w[(l + 128) * 2],   w5 = fc3_w[(l + 128) * 2 + 1];
        float w6 = fc3_w[(l + 192) * 2],   w7 = fc3_w[(l + 192) * 2 + 1];
        float h0 = (float)U.p2.hbh[s][l];
        float h1 = (float)U.p2.hbh[s][l + 64];
        float h2v = (float)U.p2.hbh[s][l + 128];
        float h3 = (float)U.p2.hbh[s][l + 192];
        float s0 = h0 * w0 + h1 * w2 + h2v * w4 + h3 * w6;
        float s1 = h0 * w1 + h1 * w3 + h2v * w5 + h3 * w7;
        #pragma unroll
        for (int off = 32; off >= 1; off >>= 1) {
            s0 += __shfl_down(s0, off, 64);
            s1 += __shfl_down(s1, off, 64);
        }
        if (l == 0) {
            int sm = smpb + s;
            if (sm < B) {
                out[sm * 2 + 0] = tanhf(s0 + fc3_b[0]);
                out[sm * 2 + 1] = tanhf(s1 + fc3_b[1]);
            }
        }
    }
}

extern "C" void kernel_launch(void* const* d_in, const int* in_sizes, int n_in,
                              void* d_out, int out_size, void* d_ws, size_t ws_size,
                              hipStream_t stream) {
    const float* state24 = (const float*)d_in[0];
    const float* Wl1 = (const float*)d_in[1];
    const float* Wr1 = (const float*)d_in[2];
    const float* att1 = (const float*)d_in[3];
    const float* b1 = (const float*)d_in[4];
    const float* Wl2 = (const float*)d_in[5];
    const float* Wr2 = (const float*)d_in[6];
    const float* att2 = (const float*)d_in[7];
    const float* b2 = (const float*)d_in[8];
    const float* fc1_w = (const float*)d_in[9];
    const float* fc1_b = (const float*)d_in[10];
    const float* fc2_w = (const float*)d_in[11];
    const float* fc2_b = (const float*)d_in[12];
    const float* fc3_w = (const float*)d_in[13];
    const float* fc3_b = (const float*)d_in[14];
    float* out = (float*)d_out;

    h8* ws = (h8*)d_ws;                 // 14336 h8 = 224 KiB
    const h8* wsL = ws;
    const h8* wsR = ws + 2048;
    const h8* wsF1 = ws + 4096;
    const h8* wsF2 = ws + 6144;

    pack_weights_kernel<<<56, 256, 0, stream>>>(Wl2, Wr2, fc1_w, fc2_w, ws);

    int B = in_sizes[0] / 24;
    int nb = (B + NS - 1) / NS;
    actor_fused_kernel<<<nb, 256, 0, stream>>>(
        state24, Wl1, Wr1, att1, b1, att2, b2,
        fc1_b, fc2_b, fc3_w, fc3_b,
        wsL, wsR, wsF1, wsF2, out, B);
}

// Round 16
// 111.026 us; speedup vs baseline: 1.1059x; 1.1059x over previous
//
#include <hip/hip_runtime.h>
#include <hip/hip_fp16.h>
#include <math.h>

#define PI_D 3.141592653589793

typedef _Float16 h2 __attribute__((ext_vector_type(2)));
typedef _Float16 h4 __attribute__((ext_vector_type(4)));
typedef _Float16 h8 __attribute__((ext_vector_type(8)));
typedef unsigned short us8 __attribute__((ext_vector_type(8)));
typedef __fp16 f16v2 __attribute__((ext_vector_type(2)));
typedef __fp16 f16v8 __attribute__((ext_vector_type(8)));
typedef float f32x4 __attribute__((ext_vector_type(4)));

#define STR1 264     // gl1h/gr1h row stride in halves (528 B; 33 h8)
#define STR2H 72     // gl2h/gr2h fp16 row stride in halves (144 B)

#define SV(v, a, b) __builtin_shufflevector(v, v, a, b)

static __device__ __forceinline__ h2 pack_h2(float a, float b) {
    return __builtin_bit_cast(h2, __builtin_amdgcn_cvt_pkrtz(a, b));
}

static __device__ __forceinline__ float fdot2(h2 a, h2 b, float c) {
    return __builtin_amdgcn_fdot2(__builtin_bit_cast(f16v2, a),
                                  __builtin_bit_cast(f16v2, b), c, false);
}

static __device__ __forceinline__ h8 habs8(h8 x) {
    us8 u = __builtin_bit_cast(us8, x);
    us8 m = {0x7fff, 0x7fff, 0x7fff, 0x7fff, 0x7fff, 0x7fff, 0x7fff, 0x7fff};
    return __builtin_bit_cast(h8, (us8)(u & m));
}

static __device__ __forceinline__ f32x4 mfma16(h8 a, h8 b, f32x4 c) {
    return __builtin_amdgcn_mfma_f32_16x16x32_f16(
        __builtin_bit_cast(f16v8, a), __builtin_bit_cast(f16v8, b), c, 0, 0, 0);
}

static __device__ __forceinline__ void wave_fence() {
    asm volatile("" ::: "memory");
#if __has_builtin(__builtin_amdgcn_wave_barrier)
    __builtin_amdgcn_wave_barrier();
#endif
    asm volatile("" ::: "memory");
}

// ---- pre-pass: pack weights to fp16 (round-10 layouts) ----
__global__ __launch_bounds__(256) void pack_weights_kernel(
    const float* __restrict__ Wl2, const float* __restrict__ Wr2,
    const float* __restrict__ fc1_w, const float* __restrict__ fc2_w,
    h8* __restrict__ ws)
{
    int idx = blockIdx.x * 256 + threadIdx.x;
    if (idx < 4096) {
        const float* W = idx < 2048 ? Wl2 : Wr2;
        int t = idx & 2047;
        int ntile = t >> 9, rem = t & 511;
        int kchunk = rem >> 6, lane = rem & 63;
        int n = ntile * 16 + (lane & 15);
        int k0 = kchunk * 32 + (lane >> 4) * 8;
        h8 o;
        #pragma unroll
        for (int j = 0; j < 8; ++j) o[j] = (_Float16)W[(k0 + j) * 64 + n];
        ws[idx] = o;
    } else if (idx < 6144) {
        int t = idx - 4096;
        int k2 = t >> 6, c = t & 63;
        h8 o;
        #pragma unroll
        for (int q = 0; q < 4; ++q) {
            o[2 * q]     = (_Float16)fc1_w[(2 * k2) * 256 + 4 * c + q];
            o[2 * q + 1] = (_Float16)fc1_w[(2 * k2 + 1) * 256 + 4 * c + q];
        }
        ws[idx] = o;
    } else {
        int t = idx - 6144;
        int k2 = t >> 6, c = t & 63;
        h8 o;
        #pragma unroll
        for (int q = 0; q < 4; ++q) {
            o[2 * q]     = (_Float16)fc2_w[(2 * k2) * 256 + 4 * c + q];
            o[2 * q + 1] = (_Float16)fc2_w[(2 * k2 + 1) * 256 + 4 * c + q];
        }
        ws[idx] = o;
    }
}

__global__ __launch_bounds__(256, 2) void actor_fused_kernel(
    const float* __restrict__ state24,
    const float* __restrict__ Wl1, const float* __restrict__ Wr1,
    const float* __restrict__ att1, const float* __restrict__ b1,
    const float* __restrict__ att2, const float* __restrict__ b2,
    const float* __restrict__ fc1_b, const float* __restrict__ fc2_b,
    const float* __restrict__ fc3_w, const float* __restrict__ fc3_b,
    const h8* __restrict__ wsL, const h8* __restrict__ wsR,
    const h8* __restrict__ wsF1, const h8* __restrict__ wsF2,
    float* __restrict__ out, int B)
{
    const int bix = blockIdx.x;
    const int tid = threadIdx.x;
    const int smp0 = 2 * bix;
    if (smp0 >= B) return;
    const int smp1 = (smp0 + 1 < B) ? smp0 + 1 : smp0;

    __shared__ float sinL[20], cosL[20], laserL[2][20], robotL[2][4];
    __shared__ __align__(16) h2 attLh[128];
    __shared__ __align__(16) h2 att2Lh[32];
    __shared__ __align__(16) _Float16 gr1h[2][22 * STR1];
    __shared__ __align__(16) union {
        struct { _Float16 gl1h[2][22 * STR1];
                 float ePf[2][128 * 24];
                 float uv[2][168]; } p1;
        struct { _Float16 gl2h[2][21 * STR2H];
                 _Float16 gr2h[2][21 * STR2H];
                 _Float16 gl2hT[2][64 * 32];
                 float e2[2][32 * 24];
                 float u2v2[2][42];
                 float red[2][4][256];
                 _Float16 nfvh[2][64]; _Float16 hah[2][256]; _Float16 hbh[2][256]; } p2;
    } U;

    // ---- setup ----
    if (tid < 20) {
        double step = (PI_D + 0.03) / 20.0;
        float bound = (float)(-PI_D / 2.0 - 0.03 + (double)tid * step);
        float ang = bound + (float)(PI_D / 20.0);
        sinL[tid] = sinf(ang);
        cosL[tid] = cosf(ang);
        laserL[0][tid] = state24[smp0 * 24 + tid] * 0.1f;
        laserL[1][tid] = state24[smp1 * 24 + tid] * 0.1f;
    }
    if (tid >= 32 && tid < 40) {
        int s = (tid - 32) >> 2, q = (tid - 32) & 3;
        robotL[s][q] = state24[(s ? smp1 : smp0) * 24 + 20 + q];
    }
    if (tid < 128) {
        float2 ap = ((const float2*)att1)[tid];
        attLh[tid] = pack_h2(0.4f * ap.x, 0.4f * ap.y);
    }
    if (tid >= 128 && tid < 160) {
        float2 ap = ((const float2*)att2)[tid - 128];
        att2Lh[tid - 128] = pack_h2(0.4f * ap.x, 0.4f * ap.y);
    }
    __syncthreads();

    // ================= L1 block: wave h owns head h, both samples =================
    {
        const int h = tid >> 6;
        const int lane = tid & 63;

        // ---- transform1: weights loaded once, used for both samples ----
        {
            const int cp = lane & 31;
            const int half = lane >> 5;
            const int d2 = h * 32 + cp;
            float2 wl[7], wr[7];
            #pragma unroll
            for (int k = 0; k < 7; k++) {
                wl[k] = ((const float2*)Wl1)[k * 128 + d2];
                wr[k] = ((const float2*)Wr1)[k * 128 + d2];
            }
            if (half == 0) {
                h2 zz2 = {};
                #pragma unroll
                for (int s = 0; s < 2; ++s) {
                    ((h2*)(U.p1.gl1h[s] + 21 * STR1))[d2] = zz2;
                    ((h2*)(gr1h[s] + 21 * STR1))[d2] = zz2;
                }
            }
            const int base = half * 11;
            #pragma unroll
            for (int nn = 0; nn < 11; ++nn) {
                int node = base + nn;
                if (node < 21) {
                    #pragma unroll
                    for (int s = 0; s < 2; ++s) {
                        float a0, a1, b0, b1v;
                        if (node < 20) {
                            float l = laserL[s][node], sv = sinL[node], c = cosL[node];
                            a0 = l * wl[0].x + sv * wl[1].x + c * wl[2].x;
                            a1 = l * wl[0].y + sv * wl[1].y + c * wl[2].y;
                            b0 = l * wr[0].x + sv * wr[1].x + c * wr[2].x;
                            b1v = l * wr[0].y + sv * wr[1].y + c * wr[2].y;
                        } else {
                            float r0 = robotL[s][0], r1 = robotL[s][1], r2 = robotL[s][2], r3 = robotL[s][3];
                            a0 = r0 * wl[3].x + r1 * wl[4].x + r2 * wl[5].x + r3 * wl[6].x;
                            a1 = r0 * wl[3].y + r1 * wl[4].y + r2 * wl[5].y + r3 * wl[6].y;
                            b0 = r0 * wr[3].x + r1 * wr[4].x + r2 * wr[5].x + r3 * wr[6].x;
                            b1v = r0 * wr[3].y + r1 * wr[4].y + r2 * wr[5].y + r3 * wr[6].y;
                        }
                        ((h2*)(U.p1.gl1h[s] + node * STR1))[d2] = pack_h2(a0, a1);
                        ((h2*)(gr1h[s] + node * STR1))[d2] = pack_h2(b0, b1v);
                    }
                }
            }
        }
        wave_fence();

        // ---- logits1 (abs part) + u/v, both samples ----
        {
            h2 ar[32];
            #pragma unroll
            for (int q = 0; q < 32; ++q) ar[q] = attLh[h * 32 + q];

            #pragma unroll
            for (int s = 0; s < 2; ++s) {
                for (int it = 0; it < 7; ++it) {
                    int q = it * 64 + lane;
                    if (q < 441) {
                        int i = q / 21;
                        int j = q - i * 21;
                        const h8* gA8 = (const h8*)(U.p1.gl1h[s] + j * STR1 + h * 64);
                        const h8* gB8 = (const h8*)(gr1h[s] + i * STR1 + h * 64);
                        float m0 = 0.f, m1 = 0.f;
                        #pragma unroll
                        for (int ch = 0; ch < 8; ++ch) {
                            h8 x = gA8[ch] + gB8[ch];
                            h8 ax = habs8(x);
                            m0 = fdot2(SV(ax, 0, 1), ar[ch * 4 + 0], m0);
                            m1 = fdot2(SV(ax, 2, 3), ar[ch * 4 + 1], m1);
                            m0 = fdot2(SV(ax, 4, 5), ar[ch * 4 + 2], m0);
                            m1 = fdot2(SV(ax, 6, 7), ar[ch * 4 + 3], m1);
                        }
                        U.p1.ePf[s][(h * 32 + i) * 24 + j] = m0 + m1;
                    }
                }
            }
            if (lane < 42) {
                int isV = lane >= 21;
                int idx = isV ? lane - 21 : lane;
                #pragma unroll
                for (int s = 0; s < 2; ++s) {
                    const _Float16* rowp = (isV ? (const _Float16*)gr1h[s]
                                                : (const _Float16*)U.p1.gl1h[s]) + idx * STR1 + h * 64;
                    const h8* row8 = (const h8*)rowp;
                    float l0 = 0.f, l1 = 0.f;
                    #pragma unroll
                    for (int ch = 0; ch < 8; ++ch) {
                        h8 g = row8[ch];
                        l0 = fdot2(SV(g, 0, 1), ar[ch * 4 + 0], l0);
                        l1 = fdot2(SV(g, 2, 3), ar[ch * 4 + 1], l1);
                        l0 = fdot2(SV(g, 4, 5), ar[ch * 4 + 2], l0);
                        l1 = fdot2(SV(g, 6, 7), ar[ch * 4 + 3], l1);
                    }
                    U.p1.uv[s][(isV ? 84 : 0) + h * 21 + idx] = l0 + l1;
                }
            }
        }
        wave_fence();

        // ---- softmax1: lanes 0..20 s=0, 21..41 s=1; zero rows 21..31 both samples ----
        if (lane < 42) {
            int s = lane >= 21;
            int i = lane - s * 21;
            int r = h * 32 + i;
            float* row = U.p1.ePf[s] + r * 24;
            const float* uu = U.p1.uv[s] + h * 21;
            float vi = 1.5f * U.p1.uv[s][84 + h * 21 + i];
            float ebuf[21];
            float m = -1e30f;
            #pragma unroll
            for (int j = 0; j < 21; j++) {
                float e = row[j] + 1.5f * uu[j] + vi;
                ebuf[j] = e;
                m = fmaxf(m, e);
            }
            float sum = 0.f;
            #pragma unroll
            for (int j = 0; j < 21; j++) { float v = __expf(ebuf[j] - m); ebuf[j] = v; sum += v; }
            float rinv = 1.f / sum;
            h8* hp8 = (h8*)(U.p1.ePf[s]) + r * 6;
            h8 o0, o1, o2;
            #pragma unroll
            for (int q = 0; q < 8; ++q) o0[q] = (_Float16)(ebuf[q] * rinv);
            #pragma unroll
            for (int q = 0; q < 8; ++q) o1[q] = (_Float16)(ebuf[8 + q] * rinv);
            #pragma unroll
            for (int q = 0; q < 5; ++q) o2[q] = (_Float16)(ebuf[16 + q] * rinv);
            o2[5] = (_Float16)0.f; o2[6] = (_Float16)0.f; o2[7] = (_Float16)0.f;
            h8 zz = {};
            hp8[0] = o0; hp8[1] = o1; hp8[2] = o2;
            hp8[3] = zz; hp8[4] = zz; hp8[5] = zz;
        }
        {   // zero fp16 A-frag rows (h, 21..31) x 2 samples: 132 h8 slots
            h8 zz = {};
            for (int z = lane; z < 132; z += 64) {
                int s = z >= 66;
                int zz2 = z - s * 66;
                int rr = zz2 / 6, slot = zz2 - rr * 6;
                ((h8*)U.p1.ePf[s])[(h * 32 + 21 + rr) * 6 + slot] = zz;
            }
        }
        wave_fence();

        // ---- agg1 via MFMA, both samples; bias loaded once ----
        {
            const int mcol = lane & 15;
            const int quad = lane >> 4;
            h8 A0s[2], A1s[2];
            #pragma unroll
            for (int s = 0; s < 2; ++s) {
                const h8* Af = (const h8*)U.p1.ePf[s];
                A0s[s] = Af[(h * 32 + mcol) * 6 + quad];
                A1s[s] = Af[(h * 32 + 16 + mcol) * 6 + quad];
            }
            int rowoff[8];
            #pragma unroll
            for (int jj = 0; jj < 8; ++jj) {
                int rr = quad * 8 + jj;
                rowoff[jj] = (rr > 21 ? 21 : rr) * STR1;
            }
            const int colbase = h * 64 + mcol;
            f32x4 z4 = {0.f, 0.f, 0.f, 0.f};
            #pragma unroll
            for (int t = 0; t < 4; ++t) {
                int col = colbase + t * 16;
                float bb = b1[col];
                #pragma unroll
                for (int s = 0; s < 2; ++s) {
                    h8 bv;
                    #pragma unroll
                    for (int jj = 0; jj < 8; ++jj) bv[jj] = U.p1.gl1h[s][rowoff[jj] + col];
                    f32x4 d0 = mfma16(A0s[s], bv, z4);
                    f32x4 d1 = mfma16(A1s[s], bv, z4);
                    #pragma unroll
                    for (int r = 0; r < 4; ++r) {
                        int n0 = quad * 4 + r;
                        float v = d0[r] + bb;
                        v = v > 0.f ? v : __expf(v) - 1.f;
                        gr1h[s][n0 * STR1 + col] = (_Float16)v;
                        int n1 = 16 + quad * 4 + r;
                        if (n1 < 21) {
                            float w2 = d1[r] + bb;
                            w2 = w2 > 0.f ? w2 : __expf(w2) - 1.f;
                            gr1h[s][n1 * STR1 + col] = (_Float16)w2;
                        }
                    }
                }
            }
        }
    }
    __syncthreads();
    // ================= end L1 block =================

    // ---- layer-2 transforms via MFMA; B-frags loaded once per kc, used by both samples ----
    {
        const int lane = tid & 63;
        const int w = tid >> 6;
        const int mrow = lane & 15;
        const int quad = lane >> 4;
        int rowA1 = 16 + mrow; if (rowA1 > 21) rowA1 = 21;
        const h8* bL = wsL + w * 512 + lane;
        const h8* bR = wsR + w * 512 + lane;
        f32x4 aL0[2], aL1[2], aR0[2], aR1[2];
        #pragma unroll
        for (int s = 0; s < 2; ++s) {
            aL0[s] = (f32x4){0.f, 0.f, 0.f, 0.f}; aL1[s] = (f32x4){0.f, 0.f, 0.f, 0.f};
            aR0[s] = (f32x4){0.f, 0.f, 0.f, 0.f}; aR1[s] = (f32x4){0.f, 0.f, 0.f, 0.f};
        }
        #pragma unroll
        for (int kc = 0; kc < 8; ++kc) {
            h8 BL = bL[kc * 64];
            h8 BR = bR[kc * 64];
            #pragma unroll
            for (int s = 0; s < 2; ++s) {
                h8 A0 = *(const h8*)(gr1h[s] + mrow * STR1 + quad * 8 + kc * 32);
                h8 A1 = *(const h8*)(gr1h[s] + rowA1 * STR1 + quad * 8 + kc * 32);
                aL0[s] = mfma16(A0, BL, aL0[s]);
                aL1[s] = mfma16(A1, BL, aL1[s]);
                aR0[s] = mfma16(A0, BR, aR0[s]);
                aR1[s] = mfma16(A1, BR, aR1[s]);
            }
        }
        const int col = w * 16 + mrow;
        #pragma unroll
        for (int s = 0; s < 2; ++s) {
            #pragma unroll
            for (int r = 0; r < 4; ++r) {
                int row0 = quad * 4 + r;
                U.p2.gl2h[s][row0 * STR2H + col] = (_Float16)aL0[s][r];
                U.p2.gr2h[s][row0 * STR2H + col] = (_Float16)aR0[s][r];
                int row1 = 16 + row0;
                if (row1 < 21) {
                    U.p2.gl2h[s][row1 * STR2H + col] = (_Float16)aL1[s][r];
                    U.p2.gr2h[s][row1 * STR2H + col] = (_Float16)aR1[s][r];
                }
            }
            h2 lo0 = pack_h2(aL0[s][0], aL0[s][1]);
            h2 hi0 = pack_h2(aL0[s][2], aL0[s][3]);
            h4 p0 = __builtin_shufflevector(lo0, hi0, 0, 1, 2, 3);
            *(h4*)(U.p2.gl2hT[s] + col * 32 + quad * 4) = p0;
            h2 lo1 = pack_h2(aL1[s][0], aL1[s][1]);
            h2 hi1 = pack_h2(aL1[s][2], aL1[s][3]);
            h4 p1 = __builtin_shufflevector(lo1, hi1, 0, 1, 2, 3);
            *(h4*)(U.p2.gl2hT[s] + col * 32 + 16 + quad * 4) = p1;
        }
    }
    __syncthreads();

    // ---- layer-2 logits (abs part) both samples + u2/v2 in spare slots ----
    {
        h2 ar2[32];
        #pragma unroll
        for (int q = 0; q < 32; ++q) ar2[q] = att2Lh[q];

        #pragma unroll
        for (int it = 0; it < 4; ++it) {
            int t = it * 256 + tid;
            if (t < 882) {
                int s = t >= 441;
                int p = t - s * 441;
                int i = p / 21;
                int j = p - i * 21;
                const h8* gA8 = (const h8*)(U.p2.gl2h[s] + j * STR2H);
                const h8* gB8 = (const h8*)(U.p2.gr2h[s] + i * STR2H);
                float m0 = 0.f, m1 = 0.f;
                #pragma unroll
                for (int ch = 0; ch < 8; ++ch) {
                    h8 x = gA8[ch] + gB8[ch];
                    h8 ax = habs8(x);
                    m0 = fdot2(SV(ax, 0, 1), ar2[ch * 4 + 0], m0);
                    m1 = fdot2(SV(ax, 2, 3), ar2[ch * 4 + 1], m1);
                    m0 = fdot2(SV(ax, 4, 5), ar2[ch * 4 + 2], m0);
                    m1 = fdot2(SV(ax, 6, 7), ar2[ch * 4 + 3], m1);
                }
                U.p2.e2[s][i * 24 + j] = m0 + m1;
            } else if (t < 966) {
                int u = t - 882;                  // 0..83
                int s = u >= 42;
                int r = u - s * 42;
                int isV = r >= 21;
                int idx = r - isV * 21;
                const _Float16* rowp = (isV ? U.p2.gr2h[s] : U.p2.gl2h[s]) + idx * STR2H;
                const h8* row8 = (const h8*)rowp;
                float l0 = 0.f, l1 = 0.f;
                #pragma unroll
                for (int ch = 0; ch < 8; ++ch) {
                    h8 g = row8[ch];
                    l0 = fdot2(SV(g, 0, 1), ar2[ch * 4 + 0], l0);
                    l1 = fdot2(SV(g, 2, 3), ar2[ch * 4 + 1], l1);
                    l0 = fdot2(SV(g, 4, 5), ar2[ch * 4 + 2], l0);
                    l1 = fdot2(SV(g, 6, 7), ar2[ch * 4 + 3], l1);
                }
                U.p2.u2v2[s][isV * 21 + idx] = l0 + l1;
            }
        }
    }
    __syncthreads();

    // ---- softmax-2 both samples -> fp16 A-frag; zero rows 21..31 both ----
    if (tid < 42) {
        int s = tid >= 21;
        int i = tid - s * 21;
        float* row = U.p2.e2[s] + i * 24;
        const float* uu = U.p2.u2v2[s];
        float vi = 1.5f * U.p2.u2v2[s][21 + i];
        float ebuf[21];
        float m = -1e30f;
        #pragma unroll
        for (int j = 0; j < 21; j++) {
            float e = row[j] + 1.5f * uu[j] + vi;
            ebuf[j] = e;
            m = fmaxf(m, e);
        }
        float sum = 0.f;
        #pragma unroll
        for (int j = 0; j < 21; j++) { float v = __expf(ebuf[j] - m); ebuf[j] = v; sum += v; }
        float rinv = 1.f / sum;
        h8* hp8 = (h8*)(U.p2.e2[s]) + i * 6;
        h8 o0, o1, o2;
        #pragma unroll
        for (int q = 0; q < 8; ++q) o0[q] = (_Float16)(ebuf[q] * rinv);
        #pragma unroll
        for (int q = 0; q < 8; ++q) o1[q] = (_Float16)(ebuf[8 + q] * rinv);
        #pragma unroll
        for (int q = 0; q < 5; ++q) o2[q] = (_Float16)(ebuf[16 + q] * rinv);
        o2[5] = (_Float16)0.f; o2[6] = (_Float16)0.f; o2[7] = (_Float16)0.f;
        h8 zz = {};
        hp8[0] = o0; hp8[1] = o1; hp8[2] = o2;
        hp8[3] = zz; hp8[4] = zz; hp8[5] = zz;
    } else if (tid < 174) {
        int z = tid - 42;                 // 0..131: rows 21..31 x 6 slots x 2 samples
        int s = z >= 66;
        int zz2 = z - s * 66;
        int rr = zz2 / 6, slot = zz2 - rr * 6;
        h8 zz = {};
        ((h8*)U.p2.e2[s])[(21 + rr) * 6 + slot] = zz;
    }
    __syncthreads();

    // ---- agg2 + mean-pool via MFMA -> nfvh, both samples ----
    {
        const int lane = tid & 63;
        const int w = tid >> 6;
        const int mcol = lane & 15;
        const int quad = lane >> 4;
        const int col = w * 16 + mcol;
        float bb = b2[col];
        f32x4 z4 = {0.f, 0.f, 0.f, 0.f};
        #pragma unroll
        for (int s = 0; s < 2; ++s) {
            const h8* Af2 = (const h8*)U.p2.e2[s];
            h8 A0 = Af2[mcol * 6 + quad];
            h8 A1 = Af2[(16 + mcol) * 6 + quad];
            h8 bv = *(const h8*)(U.p2.gl2hT[s] + col * 32 + quad * 8);
            f32x4 d0 = mfma16(A0, bv, z4);
            f32x4 d1 = mfma16(A1, bv, z4);
            float sum = (d0[0] + d0[1]) + (d0[2] + d0[3])
                      + (d1[0] + d1[1]) + (d1[2] + d1[3]);
            sum += __shfl_xor(sum, 16, 64);
            sum += __shfl_xor(sum, 32, 64);
            if (quad == 0) U.p2.nfvh[s][col] = (_Float16)(sum * (1.f / 21.f) + bb);
        }
    }
    __syncthreads();

    // ---- FC1 (64 -> 256): weights loaded once, both samples ----
    {
        int c = tid & 63, g = tid >> 6;
        float4 acc0 = {0.f, 0.f, 0.f, 0.f}, acc1 = {0.f, 0.f, 0.f, 0.f};
        #pragma unroll
        for (int kk = 0; kk < 8; ++kk) {
            int k2 = g * 8 + kk;
            h8 w = wsF1[k2 * 64 + c];
            h2 x0 = ((const h2*)U.p2.nfvh[0])[k2];
            h2 x1 = ((const h2*)U.p2.nfvh[1])[k2];
            acc0.x = fdot2(SV(w, 0, 1), x0, acc0.x);
            acc0.y = fdot2(SV(w, 2, 3), x0, acc0.y);
            acc0.z = fdot2(SV(w, 4, 5), x0, acc0.z);
            acc0.w = fdot2(SV(w, 6, 7), x0, acc0.w);
            acc1.x = fdot2(SV(w, 0, 1), x1, acc1.x);
            acc1.y = fdot2(SV(w, 2, 3), x1, acc1.y);
            acc1.z = fdot2(SV(w, 4, 5), x1, acc1.z);
            acc1.w = fdot2(SV(w, 6, 7), x1, acc1.w);
        }
        ((float4*)U.p2.red[0][g])[c] = acc0;
        ((float4*)U.p2.red[1][g])[c] = acc1;
    }
    __syncthreads();
    {
        float bb = fc1_b[tid];
        #pragma unroll
        for (int s = 0; s < 2; ++s) {
            float v = U.p2.red[s][0][tid] + U.p2.red[s][1][tid]
                    + U.p2.red[s][2][tid] + U.p2.red[s][3][tid] + bb;
            U.p2.hah[s][tid] = (_Float16)fmaxf(v, 0.f);
        }
    }
    __syncthreads();

    // ---- FC2 (256 -> 256): weights loaded once, both samples ----
    {
        int c = tid & 63, g = tid >> 6;
        const h8* ha0 = (const h8*)U.p2.hah[0];
        const h8* ha1 = (const h8*)U.p2.hah[1];
        float4 acc0 = {0.f, 0.f, 0.f, 0.f}, acc1 = {0.f, 0.f, 0.f, 0.f};
#define FC2_STEP(q, p)                                                          \
        {                                                                       \
            int k2 = g * 32 + (q) * 4 + (p);                                    \
            h8 w = wsF2[k2 * 64 + c];                                           \
            h2 x0 = __builtin_shufflevector(xa0, xa0, 2 * (p), 2 * (p) + 1);    \
            h2 x1 = __builtin_shufflevector(xa1, xa1, 2 * (p), 2 * (p) + 1);    \
            acc0.x = fdot2(SV(w, 0, 1), x0, acc0.x);                            \
            acc0.y = fdot2(SV(w, 2, 3), x0, acc0.y);                            \
            acc0.z = fdot2(SV(w, 4, 5), x0, acc0.z);                            \
            acc0.w = fdot2(SV(w, 6, 7), x0, acc0.w);                            \
            acc1.x = fdot2(SV(w, 0, 1), x1, acc1.x);                            \
            acc1.y = fdot2(SV(w, 2, 3), x1, acc1.y);                            \
            acc1.z = fdot2(SV(w, 4, 5), x1, acc1.z);                            \
            acc1.w = fdot2(SV(w, 6, 7), x1, acc1.w);                            \
        }
        #pragma unroll
        for (int q = 0; q < 8; ++q) {
            h8 xa0 = ha0[g * 8 + q];
            h8 xa1 = ha1[g * 8 + q];
            FC2_STEP(q, 0)
            FC2_STEP(q, 1)
            FC2_STEP(q, 2)
            FC2_STEP(q, 3)
        }
#undef FC2_STEP
        ((float4*)U.p2.red[0][g])[c] = acc0;
        ((float4*)U.p2.red[1][g])[c] = acc1;
    }
    __syncthreads();
    {
        float bb = fc2_b[tid];
        #pragma unroll
        for (int s = 0; s < 2; ++s) {
            float v = U.p2.red[s][0][tid] + U.p2.red[s][1][tid]
                    + U.p2.red[s][2][tid] + U.p2.red[s][3][tid] + bb;
            U.p2.hbh[s][tid] = (_Float16)fmaxf(v, 0.f);
        }
    }
    __syncthreads();

    // ---- FC3 (256 -> 2) + tanh: 4 wave-groups = (o, s) pairs ----
    {
        int g = tid >> 6;                 // 0..3
        int o = g & 1, s = g >> 1;
        int l = tid & 63;
        float sum = 0.f;
        #pragma unroll
        for (int m = 0; m < 4; m++) {
            int k = l + 64 * m;
            sum = fmaf((float)U.p2.hbh[s][k], fc3_w[k * 2 + o], sum);
        }
        #pragma unroll
        for (int off = 32; off >= 1; off >>= 1) sum += __shfl_down(sum, off, 64);
        if (l == 0 && smp0 + s < B) out[(smp0 + s) * 2 + o] = tanhf(sum + fc3_b[o]);
    }
}

extern "C" void kernel_launch(void* const* d_in, const int* in_sizes, int n_in,
                              void* d_out, int out_size, void* d_ws, size_t ws_size,
                              hipStream_t stream) {
    const float* state24 = (const float*)d_in[0];
    const float* Wl1 = (const float*)d_in[1];
    const float* Wr1 = (const float*)d_in[2];
    const float* att1 = (const float*)d_in[3];
    const float* b1 = (const float*)d_in[4];
    const float* Wl2 = (const float*)d_in[5];
    const float* Wr2 = (const float*)d_in[6];
    const float* att2 = (const float*)d_in[7];
    const float* b2 = (const float*)d_in[8];
    const float* fc1_w = (const float*)d_in[9];
    const float* fc1_b = (const float*)d_in[10];
    const float* fc2_w = (const float*)d_in[11];
    const float* fc2_b = (const float*)d_in[12];
    const float* fc3_w = (const float*)d_in[13];
    const float* fc3_b = (const float*)d_in[14];
    float* out = (float*)d_out;

    h8* ws = (h8*)d_ws;                 // 14336 h8 = 224 KiB
    const h8* wsL = ws;
    const h8* wsR = ws + 2048;
    const h8* wsF1 = ws + 4096;
    const h8* wsF2 = ws + 6144;

    pack_weights_kernel<<<56, 256, 0, stream>>>(Wl2, Wr2, fc1_w, fc2_w, ws);

    int B = in_sizes[0] / 24;
    int nb = (B + 1) / 2;
    actor_fused_kernel<<<nb, 256, 0, stream>>>(
        state24, Wl1, Wr1, att1, b1, att2, b2,
        fc1_b, fc2_b, fc3_w, fc3_b,
        wsL, wsR, wsF1, wsF2, out, B);
}